// Round 4
// baseline (1183.789 us; speedup 1.0000x reference)
//
#include <hip/hip_runtime.h>
#include <math.h>

#define D 256
#define K 1024
#define N_PTS 65536            // 64 * 32 * 32
#define BETA 0.25f
#define ORTHO_L 10.0f

#define OUT_ELEMS 16777216     // 64*256*32*32
#define LOSS_OFF 16777216
#define IDX_OFF  16777217

// ws float layout
#define WS_SSE_VQ    0
#define WS_SSE_ORTHO 1
#define WS_B         2            // 1024 floats: ||e_k||^2
#define WS_NORM      (2 + 1024)   // 1024 floats: ||e_k||

// ---------------- kernel 1: per-code squared norms ----------------
__global__ __launch_bounds__(64) void codes_kernel(const float* __restrict__ w,
                                                   float* __restrict__ ws) {
    int k = blockIdx.x;
    int lane = threadIdx.x;                       // 0..63
    float4 v = *(const float4*)(w + (size_t)k * D + lane * 4);
    float s = v.x * v.x + v.y * v.y + v.z * v.z + v.w * v.w;
    for (int m = 32; m; m >>= 1) s += __shfl_xor(s, m, 64);
    if (lane == 0) {
        ws[WS_B + k] = s;
        ws[WS_NORM + k] = sqrtf(s);
    }
}

// ---------------- kernel 2: fused distance-GEMM + argmin ----------------
// Block: 32 points x ALL 1024 codes. 256 threads.
// Thread: tx = tid&63 (code quad base), py = tid>>6 (point octet).
// acc[8][16]: 8 points x 16 codes (codes tx*4 + m*256 + j).
// W streamed in chunks of 8 d x 1024 codes (32KB), transposed on commit.
#define MT  32
#define DCH 8
#define NCHUNK (D / DCH)

__global__ __launch_bounds__(256, 2) void argmin_kernel(const float* __restrict__ x,
                                                        const float* __restrict__ w,
                                                        const float* __restrict__ wsb,
                                                        float* __restrict__ out_idx) {
    __shared__ float Xs[D][MT];       // 32 KB, d-major
    __shared__ float Ws[DCH][K];      // 32 KB, d-major
    __shared__ float Bs[K];           // 4 KB
    __shared__ float Apart[8][MT];
    __shared__ float Ash[MT];

    int tid = threadIdx.x;
    int tx = tid & 63;                // code quad group 0..63
    int py = tid >> 6;                // point group 0..3 (== wave id)
    int p0 = py * 8;

    int n0 = blockIdx.x * MT;
    int b  = n0 >> 10;                // 1024 points per batch image
    int hw0 = n0 & 1023;

    // ---- stage X tile [32 pts][256 d] transposed into Xs[d][p] ----
    const float* xb = x + (size_t)b * (D * 1024) + hw0;
    {
        int p = tid & 31;
        int cq = tid >> 5;            // 8 channels per pass
        for (int c0 = 0; c0 < D; c0 += 8) {
            int c = c0 + cq;
            Xs[c][p] = xb[(size_t)c * 1024 + p];
        }
    }
    // ---- stage code norms into LDS ----
    *(float4*)&Bs[tid * 4] = *(const float4*)&wsb[WS_B + tid * 4];
    __syncthreads();

    // ---- A_n = sum_d x^2 (per-point), same order as v1 (bitwise stable) ----
    {
        int p = tid & 31;
        int q = tid >> 5;
        float s = 0.f;
        #pragma unroll
        for (int d = 0; d < 32; ++d) {
            float v = Xs[q * 32 + d][p];
            s += v * v;
        }
        Apart[q][p] = s;
    }
    __syncthreads();
    if (tid < MT) {
        float s = 0.f;
        #pragma unroll
        for (int q = 0; q < 8; ++q) s += Apart[q][tid];
        Ash[tid] = s;
    }

    // ---- main loop: stream W in 8-d chunks, accumulate acc[8][16] ----
    float acc[8][16];
    #pragma unroll
    for (int i = 0; i < 8; ++i)
        #pragma unroll
        for (int j = 0; j < 16; ++j) acc[i][j] = 0.f;

    int cstage = tid >> 1;            // code within 128-pass
    int dh     = (tid & 1) * 4;       // d-half 0 or 4

    float4 sreg[8];
    // prefetch chunk 0
    #pragma unroll
    for (int p = 0; p < 8; ++p)
        sreg[p] = *(const float4*)(w + (size_t)(p * 128 + cstage) * D + 0 * DCH + dh);

    for (int dc = 0; dc < NCHUNK; ++dc) {
        __syncthreads();              // prev chunk's Ws reads done (and X/Ash ready at dc=0)
        // commit sreg -> Ws (transpose). 2-way bank aliasing on writes = free.
        #pragma unroll
        for (int p = 0; p < 8; ++p) {
            int c = p * 128 + cstage;
            Ws[dh + 0][c] = sreg[p].x;
            Ws[dh + 1][c] = sreg[p].y;
            Ws[dh + 2][c] = sreg[p].z;
            Ws[dh + 3][c] = sreg[p].w;
        }
        __syncthreads();              // Ws visible
        if (dc + 1 < NCHUNK) {
            #pragma unroll
            for (int p = 0; p < 8; ++p)
                sreg[p] = *(const float4*)(w + (size_t)(p * 128 + cstage) * D + (dc + 1) * DCH + dh);
        }

        #pragma unroll
        for (int d = 0; d < DCH; ++d) {
            // X fragment: 8 points, wave-uniform address -> pure broadcast
            float4 x0 = *(const float4*)&Xs[dc * DCH + d][p0];
            float4 x1 = *(const float4*)&Xs[dc * DCH + d][p0 + 4];
            float xr[8] = {x0.x, x0.y, x0.z, x0.w, x1.x, x1.y, x1.z, x1.w};
            #pragma unroll
            for (int m = 0; m < 4; ++m) {
                // W fragment: consecutive granules across lanes -> conflict-free
                float4 wv = *(const float4*)&Ws[d][tx * 4 + m * 256];
                #pragma unroll
                for (int i = 0; i < 8; ++i) {
                    acc[i][m * 4 + 0] += xr[i] * wv.x;
                    acc[i][m * 4 + 1] += xr[i] * wv.y;
                    acc[i][m * 4 + 2] += xr[i] * wv.z;
                    acc[i][m * 4 + 3] += xr[i] * wv.w;
                }
            }
        }
    }

    // ---- epilogue: d = (A + B_k) - 2*acc, argmin with first-min tiebreak ----
    #pragma unroll
    for (int i = 0; i < 8; ++i) {
        float a = Ash[p0 + i];
        float bv = 3.4e38f;
        int   bi = 0;
        #pragma unroll
        for (int m = 0; m < 4; ++m) {
            #pragma unroll
            for (int j = 0; j < 4; ++j) {
                int k = tx * 4 + m * 256 + j;
                float t  = a + Bs[k];             // fl(A + B)
                float dv = t - 2.0f * acc[i][m * 4 + j];  // fl(.. - 2C)
                if (dv < bv) { bv = dv; bi = k; } // ascending k within lane
            }
        }
        for (int mm = 32; mm; mm >>= 1) {
            float v2 = __shfl_xor(bv, mm, 64);
            int   i2 = __shfl_xor(bi, mm, 64);
            if (v2 < bv || (v2 == bv && i2 < bi)) { bv = v2; bi = i2; }
        }
        if (tx == 0) out_idx[n0 + p0 + i] = (float)bi;
    }
}

// ---------------- kernel 3: gather + out + commitment/codebook SSE ----------------
__global__ __launch_bounds__(256) void gather_kernel(const float* __restrict__ x,
                                                     const float* __restrict__ w,
                                                     const float* __restrict__ idxf,
                                                     float* __restrict__ out,
                                                     float* __restrict__ ws) {
    __shared__ float red[256];
    int tid = threadIdx.x;
    size_t t0 = (size_t)blockIdx.x * 256 + tid;
    const size_t total4 = OUT_ELEMS / 4;
    const size_t stride = (size_t)2048 * 256;

    float sse = 0.f;
    for (size_t e4 = t0; e4 < total4; e4 += stride) {
        size_t e = e4 * 4;
        int b  = (int)(e >> 18);           // /262144
        int c  = (int)((e >> 10) & 255);
        int hw = (int)(e & 1023);
        int n  = (b << 10) + hw;

        float4 xv = *(const float4*)(x + e);
        int k0 = (int)idxf[n + 0];
        int k1 = (int)idxf[n + 1];
        int k2 = (int)idxf[n + 2];
        int k3 = (int)idxf[n + 3];
        float w0 = w[(size_t)k0 * D + c];
        float w1 = w[(size_t)k1 * D + c];
        float w2 = w[(size_t)k2 * D + c];
        float w3 = w[(size_t)k3 * D + c];
        float d0 = w0 - xv.x, d1 = w1 - xv.y, d2 = w2 - xv.z, d3 = w3 - xv.w;
        float4 ov;
        ov.x = xv.x + d0;  ov.y = xv.y + d1;   // straight-through value, same rounding as ref
        ov.z = xv.z + d2;  ov.w = xv.w + d3;
        *(float4*)(out + e) = ov;
        sse += d0 * d0 + d1 * d1 + d2 * d2 + d3 * d3;
    }

    red[tid] = sse;
    __syncthreads();
    for (int s = 128; s > 0; s >>= 1) {
        if (tid < s) red[tid] += red[tid + s];
        __syncthreads();
    }
    if (tid == 0) atomicAdd(ws + WS_SSE_VQ, red[0]);
}

// ---------------- kernel 4: orthogonality regularizer ----------------
__global__ __launch_bounds__(256) void ortho_kernel(const float* __restrict__ w,
                                                    float* __restrict__ ws) {
    __shared__ float wi[D];
    __shared__ float wsum[4];
    int i = blockIdx.x;
    int tid = threadIdx.x;
    int lane = tid & 63;
    int wid = tid >> 6;

    if (tid < 64)
        *(float4*)&wi[tid * 4] = *(const float4*)(w + (size_t)i * D + tid * 4);
    __syncthreads();

    float inv_i = 1.0f / ws[WS_NORM + i];
    float acc = 0.f;
    for (int j = wid; j < K; j += 4) {
        float4 a = *(const float4*)(w + (size_t)j * D + lane * 4);
        float4 bq = *(const float4*)&wi[lane * 4];
        float s = a.x * bq.x + a.y * bq.y + a.z * bq.z + a.w * bq.w;
        for (int m = 32; m; m >>= 1) s += __shfl_xor(s, m, 64);
        float sij = s * inv_i * (1.0f / ws[WS_NORM + j]);
        float t = sij - (j == i ? 1.0f : 0.0f);
        acc += t * t;                    // same on all lanes
    }
    if (lane == 0) wsum[wid] = acc;
    __syncthreads();
    if (tid == 0)
        atomicAdd(ws + WS_SSE_ORTHO, wsum[0] + wsum[1] + wsum[2] + wsum[3]);
}

// ---------------- kernel 5: finalize loss ----------------
__global__ void finalize_kernel(const float* __restrict__ ws, float* __restrict__ out) {
    float loss = (1.0f + BETA) * ws[WS_SSE_VQ] / (float)OUT_ELEMS
               + ORTHO_L * sqrtf(ws[WS_SSE_ORTHO]) / ((float)K * (float)K);
    out[LOSS_OFF] = loss;
}

extern "C" void kernel_launch(void* const* d_in, const int* in_sizes, int n_in,
                              void* d_out, int out_size, void* d_ws, size_t ws_size,
                              hipStream_t stream) {
    const float* x = (const float*)d_in[0];
    const float* w = (const float*)d_in[1];
    float* out = (float*)d_out;
    float* ws  = (float*)d_ws;

    hipMemsetAsync(d_ws, 0, 2 * sizeof(float), stream);
    codes_kernel<<<K, 64, 0, stream>>>(w, ws);
    argmin_kernel<<<N_PTS / MT, 256, 0, stream>>>(x, w, ws, out + IDX_OFF);
    ortho_kernel<<<K, 256, 0, stream>>>(w, ws);
    gather_kernel<<<2048, 256, 0, stream>>>(x, w, out + IDX_OFF, out, ws);
    finalize_kernel<<<1, 1, 0, stream>>>(ws, out);
}

// Round 5
// 1175.419 us; speedup vs baseline: 1.0071x; 1.0071x over previous
//
#include <hip/hip_runtime.h>
#include <math.h>

#define D 256
#define K 1024
#define N_PTS 65536            // 64 * 32 * 32
#define BETA 0.25f
#define ORTHO_L 10.0f

#define OUT_ELEMS 16777216     // 64*256*32*32
#define LOSS_OFF 16777216
#define IDX_OFF  16777217

// ws float layout
#define WS_SSE_VQ    0
#define WS_SSE_ORTHO 1
#define WS_B         2            // 1024 floats: ||e_k||^2
#define WS_NORM      (2 + 1024)   // 1024 floats: ||e_k||

// ---------------- kernel 1: per-code squared norms ----------------
__global__ __launch_bounds__(64) void codes_kernel(const float* __restrict__ w,
                                                   float* __restrict__ ws) {
    int k = blockIdx.x;
    int lane = threadIdx.x;                       // 0..63
    float4 v = *(const float4*)(w + (size_t)k * D + lane * 4);
    float s = v.x * v.x + v.y * v.y + v.z * v.z + v.w * v.w;
    for (int m = 32; m; m >>= 1) s += __shfl_xor(s, m, 64);
    if (lane == 0) {
        ws[WS_B + k] = s;
        ws[WS_NORM + k] = sqrtf(s);
    }
}

// ---------------- kernel 2: fused distance-GEMM + argmin ----------------
// Block: 32 points x ALL 1024 codes. 256 threads.
// Thread: tx = tid&63 (code quad base), py = tid>>6 (point octet).
// acc[8][16]: 8 points x 16 codes (codes tx*4 + m*256 + j).
// W streamed in chunks of 8 d x 1024 codes (32KB), transposed on commit.
// amdgpu_waves_per_eu(2,2): pin allocator budget at 256 VGPRs (2 waves/EU);
// without the max, hipcc targeted 128 VGPRs and spilled 2.4 GB to scratch (R4).
#define MT  32
#define DCH 8
#define NCHUNK (D / DCH)

__global__ void __launch_bounds__(256)
__attribute__((amdgpu_waves_per_eu(2, 2)))
argmin_kernel(const float* __restrict__ x,
              const float* __restrict__ w,
              const float* __restrict__ wsb,
              float* __restrict__ out_idx) {
    __shared__ float Xs[D][MT];       // 32 KB, d-major
    __shared__ float Ws[DCH][K];      // 32 KB, d-major
    __shared__ float Bs[K];           // 4 KB
    __shared__ float Apart[8][MT];
    __shared__ float Ash[MT];

    int tid = threadIdx.x;
    int tx = tid & 63;                // code quad group 0..63
    int py = tid >> 6;                // point group 0..3 (== wave id)
    int p0 = py * 8;

    int n0 = blockIdx.x * MT;
    int b  = n0 >> 10;                // 1024 points per batch image
    int hw0 = n0 & 1023;

    // ---- stage X tile [32 pts][256 d] transposed into Xs[d][p] ----
    const float* xb = x + (size_t)b * (D * 1024) + hw0;
    {
        int p = tid & 31;
        int cq = tid >> 5;            // 8 channels per pass
        for (int c0 = 0; c0 < D; c0 += 8) {
            int c = c0 + cq;
            Xs[c][p] = xb[(size_t)c * 1024 + p];
        }
    }
    // ---- stage code norms into LDS ----
    *(float4*)&Bs[tid * 4] = *(const float4*)&wsb[WS_B + tid * 4];
    __syncthreads();

    // ---- A_n = sum_d x^2 (per-point), same order as v1 (bitwise stable) ----
    {
        int p = tid & 31;
        int q = tid >> 5;
        float s = 0.f;
        #pragma unroll
        for (int d = 0; d < 32; ++d) {
            float v = Xs[q * 32 + d][p];
            s += v * v;
        }
        Apart[q][p] = s;
    }
    __syncthreads();
    if (tid < MT) {
        float s = 0.f;
        #pragma unroll
        for (int q = 0; q < 8; ++q) s += Apart[q][tid];
        Ash[tid] = s;
    }

    // ---- main loop: stream W in 8-d chunks, accumulate acc[8][16] ----
    float acc[8][16];
    #pragma unroll
    for (int i = 0; i < 8; ++i)
        #pragma unroll
        for (int j = 0; j < 16; ++j) acc[i][j] = 0.f;

    int cstage = tid >> 1;            // code within 128-pass
    int dh     = (tid & 1) * 4;       // d-half 0 or 4

    float4 sreg[8];
    // prefetch chunk 0
    #pragma unroll
    for (int p = 0; p < 8; ++p)
        sreg[p] = *(const float4*)(w + (size_t)(p * 128 + cstage) * D + 0 * DCH + dh);

    for (int dc = 0; dc < NCHUNK; ++dc) {
        __syncthreads();              // prev chunk's Ws reads done (and X/Ash ready at dc=0)
        // commit sreg -> Ws (transpose). 2-way bank aliasing on writes = free.
        #pragma unroll
        for (int p = 0; p < 8; ++p) {
            int c = p * 128 + cstage;
            Ws[dh + 0][c] = sreg[p].x;
            Ws[dh + 1][c] = sreg[p].y;
            Ws[dh + 2][c] = sreg[p].z;
            Ws[dh + 3][c] = sreg[p].w;
        }
        __syncthreads();              // Ws visible
        if (dc + 1 < NCHUNK) {
            #pragma unroll
            for (int p = 0; p < 8; ++p)
                sreg[p] = *(const float4*)(w + (size_t)(p * 128 + cstage) * D + (dc + 1) * DCH + dh);
        }

        #pragma unroll
        for (int d = 0; d < DCH; ++d) {
            // X fragment: 8 points, wave-uniform address -> pure broadcast
            float4 x0 = *(const float4*)&Xs[dc * DCH + d][p0];
            float4 x1 = *(const float4*)&Xs[dc * DCH + d][p0 + 4];
            #pragma unroll
            for (int m = 0; m < 4; ++m) {
                // W fragment: 64 lanes x 16B contiguous -> conflict-free
                float4 wv = *(const float4*)&Ws[d][tx * 4 + m * 256];
                acc[0][m*4+0] += x0.x * wv.x;  acc[0][m*4+1] += x0.x * wv.y;
                acc[0][m*4+2] += x0.x * wv.z;  acc[0][m*4+3] += x0.x * wv.w;
                acc[1][m*4+0] += x0.y * wv.x;  acc[1][m*4+1] += x0.y * wv.y;
                acc[1][m*4+2] += x0.y * wv.z;  acc[1][m*4+3] += x0.y * wv.w;
                acc[2][m*4+0] += x0.z * wv.x;  acc[2][m*4+1] += x0.z * wv.y;
                acc[2][m*4+2] += x0.z * wv.z;  acc[2][m*4+3] += x0.z * wv.w;
                acc[3][m*4+0] += x0.w * wv.x;  acc[3][m*4+1] += x0.w * wv.y;
                acc[3][m*4+2] += x0.w * wv.z;  acc[3][m*4+3] += x0.w * wv.w;
                acc[4][m*4+0] += x1.x * wv.x;  acc[4][m*4+1] += x1.x * wv.y;
                acc[4][m*4+2] += x1.x * wv.z;  acc[4][m*4+3] += x1.x * wv.w;
                acc[5][m*4+0] += x1.y * wv.x;  acc[5][m*4+1] += x1.y * wv.y;
                acc[5][m*4+2] += x1.y * wv.z;  acc[5][m*4+3] += x1.y * wv.w;
                acc[6][m*4+0] += x1.z * wv.x;  acc[6][m*4+1] += x1.z * wv.y;
                acc[6][m*4+2] += x1.z * wv.z;  acc[6][m*4+3] += x1.z * wv.w;
                acc[7][m*4+0] += x1.w * wv.x;  acc[7][m*4+1] += x1.w * wv.y;
                acc[7][m*4+2] += x1.w * wv.z;  acc[7][m*4+3] += x1.w * wv.w;
            }
        }
    }

    // ---- epilogue: d = (A + B_k) - 2*acc, argmin with first-min tiebreak ----
    #pragma unroll
    for (int i = 0; i < 8; ++i) {
        float a = Ash[p0 + i];
        float bv = 3.4e38f;
        int   bi = 0;
        #pragma unroll
        for (int m = 0; m < 4; ++m) {
            #pragma unroll
            for (int j = 0; j < 4; ++j) {
                int k = tx * 4 + m * 256 + j;
                float t  = a + Bs[k];             // fl(A + B)
                float dv = t - 2.0f * acc[i][m * 4 + j];  // fl(.. - 2C)
                if (dv < bv) { bv = dv; bi = k; } // ascending k within lane
            }
        }
        for (int mm = 32; mm; mm >>= 1) {
            float v2 = __shfl_xor(bv, mm, 64);
            int   i2 = __shfl_xor(bi, mm, 64);
            if (v2 < bv || (v2 == bv && i2 < bi)) { bv = v2; bi = i2; }
        }
        if (tx == 0) out_idx[n0 + p0 + i] = (float)bi;
    }
}

// ---------------- kernel 3: gather + out + commitment/codebook SSE ----------------
__global__ __launch_bounds__(256) void gather_kernel(const float* __restrict__ x,
                                                     const float* __restrict__ w,
                                                     const float* __restrict__ idxf,
                                                     float* __restrict__ out,
                                                     float* __restrict__ ws) {
    __shared__ float red[256];
    int tid = threadIdx.x;
    size_t t0 = (size_t)blockIdx.x * 256 + tid;
    const size_t total4 = OUT_ELEMS / 4;
    const size_t stride = (size_t)2048 * 256;

    float sse = 0.f;
    for (size_t e4 = t0; e4 < total4; e4 += stride) {
        size_t e = e4 * 4;
        int b  = (int)(e >> 18);           // /262144
        int c  = (int)((e >> 10) & 255);
        int hw = (int)(e & 1023);
        int n  = (b << 10) + hw;

        float4 xv = *(const float4*)(x + e);
        int k0 = (int)idxf[n + 0];
        int k1 = (int)idxf[n + 1];
        int k2 = (int)idxf[n + 2];
        int k3 = (int)idxf[n + 3];
        float w0 = w[(size_t)k0 * D + c];
        float w1 = w[(size_t)k1 * D + c];
        float w2 = w[(size_t)k2 * D + c];
        float w3 = w[(size_t)k3 * D + c];
        float d0 = w0 - xv.x, d1 = w1 - xv.y, d2 = w2 - xv.z, d3 = w3 - xv.w;
        float4 ov;
        ov.x = xv.x + d0;  ov.y = xv.y + d1;   // straight-through value, same rounding as ref
        ov.z = xv.z + d2;  ov.w = xv.w + d3;
        *(float4*)(out + e) = ov;
        sse += d0 * d0 + d1 * d1 + d2 * d2 + d3 * d3;
    }

    red[tid] = sse;
    __syncthreads();
    for (int s = 128; s > 0; s >>= 1) {
        if (tid < s) red[tid] += red[tid + s];
        __syncthreads();
    }
    if (tid == 0) atomicAdd(ws + WS_SSE_VQ, red[0]);
}

// ---------------- kernel 4: orthogonality regularizer ----------------
__global__ __launch_bounds__(256) void ortho_kernel(const float* __restrict__ w,
                                                    float* __restrict__ ws) {
    __shared__ float wi[D];
    __shared__ float wsum[4];
    int i = blockIdx.x;
    int tid = threadIdx.x;
    int lane = tid & 63;
    int wid = tid >> 6;

    if (tid < 64)
        *(float4*)&wi[tid * 4] = *(const float4*)(w + (size_t)i * D + tid * 4);
    __syncthreads();

    float inv_i = 1.0f / ws[WS_NORM + i];
    float acc = 0.f;
    for (int j = wid; j < K; j += 4) {
        float4 a = *(const float4*)(w + (size_t)j * D + lane * 4);
        float4 bq = *(const float4*)&wi[lane * 4];
        float s = a.x * bq.x + a.y * bq.y + a.z * bq.z + a.w * bq.w;
        for (int m = 32; m; m >>= 1) s += __shfl_xor(s, m, 64);
        float sij = s * inv_i * (1.0f / ws[WS_NORM + j]);
        float t = sij - (j == i ? 1.0f : 0.0f);
        acc += t * t;                    // same on all lanes
    }
    if (lane == 0) wsum[wid] = acc;
    __syncthreads();
    if (tid == 0)
        atomicAdd(ws + WS_SSE_ORTHO, wsum[0] + wsum[1] + wsum[2] + wsum[3]);
}

// ---------------- kernel 5: finalize loss ----------------
__global__ void finalize_kernel(const float* __restrict__ ws, float* __restrict__ out) {
    float loss = (1.0f + BETA) * ws[WS_SSE_VQ] / (float)OUT_ELEMS
               + ORTHO_L * sqrtf(ws[WS_SSE_ORTHO]) / ((float)K * (float)K);
    out[LOSS_OFF] = loss;
}

extern "C" void kernel_launch(void* const* d_in, const int* in_sizes, int n_in,
                              void* d_out, int out_size, void* d_ws, size_t ws_size,
                              hipStream_t stream) {
    const float* x = (const float*)d_in[0];
    const float* w = (const float*)d_in[1];
    float* out = (float*)d_out;
    float* ws  = (float*)d_ws;

    hipMemsetAsync(d_ws, 0, 2 * sizeof(float), stream);
    codes_kernel<<<K, 64, 0, stream>>>(w, ws);
    argmin_kernel<<<N_PTS / MT, 256, 0, stream>>>(x, w, ws, out + IDX_OFF);
    ortho_kernel<<<K, 256, 0, stream>>>(w, ws);
    gather_kernel<<<2048, 256, 0, stream>>>(x, w, out + IDX_OFF, out, ws);
    finalize_kernel<<<1, 1, 0, stream>>>(ws, out);
}

// Round 6
// 736.013 us; speedup vs baseline: 1.6084x; 1.5970x over previous
//
#include <hip/hip_runtime.h>
#include <math.h>

#define D 256
#define K 1024
#define N_PTS 65536            // 64 * 32 * 32
#define BETA 0.25f
#define ORTHO_L 10.0f

#define OUT_ELEMS 16777216     // 64*256*32*32
#define LOSS_OFF 16777216
#define IDX_OFF  16777217

// ws float layout
#define WS_SSE_VQ    0
#define WS_SSE_ORTHO 1
#define WS_B         2            // 1024 floats: ||e_k||^2
#define WS_NORM      (2 + 1024)   // 1024 floats: ||e_k||

// ---------------- kernel 1: per-code squared norms ----------------
__global__ __launch_bounds__(64) void codes_kernel(const float* __restrict__ w,
                                                   float* __restrict__ ws) {
    int k = blockIdx.x;
    int lane = threadIdx.x;                       // 0..63
    float4 v = *(const float4*)(w + (size_t)k * D + lane * 4);
    float s = v.x * v.x + v.y * v.y + v.z * v.z + v.w * v.w;
    for (int m = 32; m; m >>= 1) s += __shfl_xor(s, m, 64);
    if (lane == 0) {
        ws[WS_B + k] = s;
        ws[WS_NORM + k] = sqrtf(s);
    }
}

// ---------------- kernel 2: fused distance-GEMM + argmin ----------------
// Block: 32 points x 512 codes at a time (two halves looped in-kernel).
// 256 threads. Thread: tx = tid&63 (code quad), py = tid>>6 (point octet).
// acc[8][8]: 8 points x 8 codes -> 64 VGPR live accumulators (fits the
// 128-VGPR allocation hipcc insists on; R4/R5's acc[8][16]=128 spilled
// 2.35 GB/dispatch to scratch).
// W streamed in chunks of [8 d][512 codes] (16 KB), transposed on commit.
// LDS ~53 KB -> 3 blocks/CU.
#define MT  32
#define DCH 8
#define KH  512                   // codes per half
#define NCHUNK 64                 // 2 halves * 32 d-chunks

__global__ __launch_bounds__(256) void argmin_kernel(const float* __restrict__ x,
                                                     const float* __restrict__ w,
                                                     const float* __restrict__ wsb,
                                                     float* __restrict__ out_idx) {
    __shared__ float Xs[D][MT];       // 32 KB, d-major
    __shared__ float Ws[DCH][KH];     // 16 KB, d-major
    __shared__ float Bs[K];           // 4 KB
    __shared__ float Apart[8][MT];
    __shared__ float Ash[MT];

    int tid = threadIdx.x;
    int tx = tid & 63;                // code quad group 0..63
    int py = tid >> 6;                // point group 0..3 (== wave id)
    int p0 = py * 8;

    int n0 = blockIdx.x * MT;
    int b  = n0 >> 10;                // 1024 points per batch image
    int hw0 = n0 & 1023;

    // ---- stage X tile [32 pts][256 d] transposed into Xs[d][p] ----
    const float* xb = x + (size_t)b * (D * 1024) + hw0;
    {
        int p = tid & 31;
        int cq = tid >> 5;            // 8 channels per pass
        for (int c0 = 0; c0 < D; c0 += 8) {
            int c = c0 + cq;
            Xs[c][p] = xb[(size_t)c * 1024 + p];
        }
    }
    // ---- stage code norms into LDS ----
    *(float4*)&Bs[tid * 4] = *(const float4*)&wsb[WS_B + tid * 4];
    __syncthreads();

    // ---- A_n = sum_d x^2 (per-point), same order as R1 (bitwise stable) ----
    {
        int p = tid & 31;
        int q = tid >> 5;
        float s = 0.f;
        #pragma unroll
        for (int d = 0; d < 32; ++d) {
            float v = Xs[q * 32 + d][p];
            s += v * v;
        }
        Apart[q][p] = s;
    }
    __syncthreads();
    if (tid < MT) {
        float s = 0.f;
        #pragma unroll
        for (int q = 0; q < 8; ++q) s += Apart[q][tid];
        Ash[tid] = s;
    }

    float acc[8][8];
    #pragma unroll
    for (int i = 0; i < 8; ++i)
        #pragma unroll
        for (int j = 0; j < 8; ++j) acc[i][j] = 0.f;

    float bestv[8];
    int   besti[8];
    #pragma unroll
    for (int i = 0; i < 8; ++i) { bestv[i] = 3.4e38f; besti[i] = 0; }

    int cstage = tid >> 1;            // code 0..127 within 128-group
    int dh     = (tid & 1) * 4;       // d-half 0 or 4

    // chunk t: half = t>>5 (code base half*512), d-range (t&31)*8
    float4 sreg[4];
    #pragma unroll
    for (int p = 0; p < 4; ++p)
        sreg[p] = *(const float4*)(w + (size_t)(p * 128 + cstage) * D + dh);

    for (int t = 0; t < NCHUNK; ++t) {
        __syncthreads();              // prev chunk's Ws reads done
        #pragma unroll
        for (int p = 0; p < 4; ++p) {
            int c = p * 128 + cstage;
            Ws[dh + 0][c] = sreg[p].x;
            Ws[dh + 1][c] = sreg[p].y;
            Ws[dh + 2][c] = sreg[p].z;
            Ws[dh + 3][c] = sreg[p].w;
        }
        __syncthreads();              // Ws visible
        if (t + 1 < NCHUNK) {
            int half = (t + 1) >> 5;
            int dc   = (t + 1) & 31;
            #pragma unroll
            for (int p = 0; p < 4; ++p)
                sreg[p] = *(const float4*)(w + (size_t)(half * KH + p * 128 + cstage) * D + dc * DCH + dh);
        }

        int dbase = (t & 31) * DCH;
        #pragma unroll
        for (int d = 0; d < DCH; ++d) {
            // X fragment: 8 points, wave-uniform address -> pure broadcast
            float4 x0 = *(const float4*)&Xs[dbase + d][p0];
            float4 x1 = *(const float4*)&Xs[dbase + d][p0 + 4];
            #pragma unroll
            for (int m = 0; m < 2; ++m) {
                // W fragment: 64 lanes x 16B contiguous -> conflict-free
                float4 wv = *(const float4*)&Ws[d][tx * 4 + m * 256];
                acc[0][m*4+0] += x0.x * wv.x;  acc[0][m*4+1] += x0.x * wv.y;
                acc[0][m*4+2] += x0.x * wv.z;  acc[0][m*4+3] += x0.x * wv.w;
                acc[1][m*4+0] += x0.y * wv.x;  acc[1][m*4+1] += x0.y * wv.y;
                acc[1][m*4+2] += x0.y * wv.z;  acc[1][m*4+3] += x0.y * wv.w;
                acc[2][m*4+0] += x0.z * wv.x;  acc[2][m*4+1] += x0.z * wv.y;
                acc[2][m*4+2] += x0.z * wv.z;  acc[2][m*4+3] += x0.z * wv.w;
                acc[3][m*4+0] += x0.w * wv.x;  acc[3][m*4+1] += x0.w * wv.y;
                acc[3][m*4+2] += x0.w * wv.z;  acc[3][m*4+3] += x0.w * wv.w;
                acc[4][m*4+0] += x1.x * wv.x;  acc[4][m*4+1] += x1.x * wv.y;
                acc[4][m*4+2] += x1.x * wv.z;  acc[4][m*4+3] += x1.x * wv.w;
                acc[5][m*4+0] += x1.y * wv.x;  acc[5][m*4+1] += x1.y * wv.y;
                acc[5][m*4+2] += x1.y * wv.z;  acc[5][m*4+3] += x1.y * wv.w;
                acc[6][m*4+0] += x1.z * wv.x;  acc[6][m*4+1] += x1.z * wv.y;
                acc[6][m*4+2] += x1.z * wv.z;  acc[6][m*4+3] += x1.z * wv.w;
                acc[7][m*4+0] += x1.w * wv.x;  acc[7][m*4+1] += x1.w * wv.y;
                acc[7][m*4+2] += x1.w * wv.z;  acc[7][m*4+3] += x1.w * wv.w;
            }
        }

        if ((t & 31) == 31) {
            // half complete: fold into running argmin, then reset acc.
            int half = t >> 5;
            int kb = half * KH + tx * 4;
            #pragma unroll
            for (int i = 0; i < 8; ++i) {
                float a = Ash[p0 + i];
                #pragma unroll
                for (int m = 0; m < 2; ++m) {
                    #pragma unroll
                    for (int j = 0; j < 4; ++j) {
                        int gk = kb + m * 256 + j;        // ascending within lane & across halves
                        float tt = a + Bs[gk];            // fl(A + B)
                        float dv = tt - 2.0f * acc[i][m * 4 + j];  // fl(.. - 2C)
                        if (dv < bestv[i]) { bestv[i] = dv; besti[i] = gk; }
                        acc[i][m * 4 + j] = 0.f;
                    }
                }
            }
        }
    }

    // reduce across the 64 lanes (codes) of the wave, first-min tiebreak
    #pragma unroll
    for (int i = 0; i < 8; ++i) {
        float v = bestv[i];
        int ix = besti[i];
        for (int mm = 32; mm; mm >>= 1) {
            float v2 = __shfl_xor(v, mm, 64);
            int   i2 = __shfl_xor(ix, mm, 64);
            if (v2 < v || (v2 == v && i2 < ix)) { v = v2; ix = i2; }
        }
        if (tx == 0) out_idx[n0 + p0 + i] = (float)ix;
    }
}

// ---------------- kernel 3: gather + out + commitment/codebook SSE ----------------
__global__ __launch_bounds__(256) void gather_kernel(const float* __restrict__ x,
                                                     const float* __restrict__ w,
                                                     const float* __restrict__ idxf,
                                                     float* __restrict__ out,
                                                     float* __restrict__ ws) {
    __shared__ float red[256];
    int tid = threadIdx.x;
    size_t t0 = (size_t)blockIdx.x * 256 + tid;
    const size_t total4 = OUT_ELEMS / 4;
    const size_t stride = (size_t)2048 * 256;

    float sse = 0.f;
    for (size_t e4 = t0; e4 < total4; e4 += stride) {
        size_t e = e4 * 4;
        int b  = (int)(e >> 18);           // /262144
        int c  = (int)((e >> 10) & 255);
        int hw = (int)(e & 1023);
        int n  = (b << 10) + hw;

        float4 xv = *(const float4*)(x + e);
        int k0 = (int)idxf[n + 0];
        int k1 = (int)idxf[n + 1];
        int k2 = (int)idxf[n + 2];
        int k3 = (int)idxf[n + 3];
        float w0 = w[(size_t)k0 * D + c];
        float w1 = w[(size_t)k1 * D + c];
        float w2 = w[(size_t)k2 * D + c];
        float w3 = w[(size_t)k3 * D + c];
        float d0 = w0 - xv.x, d1 = w1 - xv.y, d2 = w2 - xv.z, d3 = w3 - xv.w;
        float4 ov;
        ov.x = xv.x + d0;  ov.y = xv.y + d1;   // straight-through value, same rounding as ref
        ov.z = xv.z + d2;  ov.w = xv.w + d3;
        *(float4*)(out + e) = ov;
        sse += d0 * d0 + d1 * d1 + d2 * d2 + d3 * d3;
    }

    red[tid] = sse;
    __syncthreads();
    for (int s = 128; s > 0; s >>= 1) {
        if (tid < s) red[tid] += red[tid + s];
        __syncthreads();
    }
    if (tid == 0) atomicAdd(ws + WS_SSE_VQ, red[0]);
}

// ---------------- kernel 4: orthogonality regularizer ----------------
__global__ __launch_bounds__(256) void ortho_kernel(const float* __restrict__ w,
                                                    float* __restrict__ ws) {
    __shared__ float wi[D];
    __shared__ float wsum[4];
    int i = blockIdx.x;
    int tid = threadIdx.x;
    int lane = tid & 63;
    int wid = tid >> 6;

    if (tid < 64)
        *(float4*)&wi[tid * 4] = *(const float4*)(w + (size_t)i * D + tid * 4);
    __syncthreads();

    float inv_i = 1.0f / ws[WS_NORM + i];
    float acc = 0.f;
    for (int j = wid; j < K; j += 4) {
        float4 a = *(const float4*)(w + (size_t)j * D + lane * 4);
        float4 bq = *(const float4*)&wi[lane * 4];
        float s = a.x * bq.x + a.y * bq.y + a.z * bq.z + a.w * bq.w;
        for (int m = 32; m; m >>= 1) s += __shfl_xor(s, m, 64);
        float sij = s * inv_i * (1.0f / ws[WS_NORM + j]);
        float t = sij - (j == i ? 1.0f : 0.0f);
        acc += t * t;                    // same on all lanes
    }
    if (lane == 0) wsum[wid] = acc;
    __syncthreads();
    if (tid == 0)
        atomicAdd(ws + WS_SSE_ORTHO, wsum[0] + wsum[1] + wsum[2] + wsum[3]);
}

// ---------------- kernel 5: finalize loss ----------------
__global__ void finalize_kernel(const float* __restrict__ ws, float* __restrict__ out) {
    float loss = (1.0f + BETA) * ws[WS_SSE_VQ] / (float)OUT_ELEMS
               + ORTHO_L * sqrtf(ws[WS_SSE_ORTHO]) / ((float)K * (float)K);
    out[LOSS_OFF] = loss;
}

extern "C" void kernel_launch(void* const* d_in, const int* in_sizes, int n_in,
                              void* d_out, int out_size, void* d_ws, size_t ws_size,
                              hipStream_t stream) {
    const float* x = (const float*)d_in[0];
    const float* w = (const float*)d_in[1];
    float* out = (float*)d_out;
    float* ws  = (float*)d_ws;

    hipMemsetAsync(d_ws, 0, 2 * sizeof(float), stream);
    codes_kernel<<<K, 64, 0, stream>>>(w, ws);
    argmin_kernel<<<N_PTS / MT, 256, 0, stream>>>(x, w, ws, out + IDX_OFF);
    ortho_kernel<<<K, 256, 0, stream>>>(w, ws);
    gather_kernel<<<2048, 256, 0, stream>>>(x, w, out + IDX_OFF, out, ws);
    finalize_kernel<<<1, 1, 0, stream>>>(ws, out);
}